// Round 10
// baseline (541.600 us; speedup 1.0000x reference)
//
#include <hip/hip_runtime.h>
#include <hip/hip_bf16.h>

typedef __attribute__((ext_vector_type(8))) short short8;
typedef __attribute__((ext_vector_type(4))) float f32x4;

#define MFMA_BF16_16x16x32(a,b,c) __builtin_amdgcn_mfma_f32_16x16x32_bf16((a),(b),(c),0,0,0)

// Problem constants
constexpr int B_  = 4;
constexpr int S_  = 2048;
constexpr int H_  = 16;
constexpr int DH_ = 64;
constexpr int D_  = 1024;
constexpr int M_  = B_ * S_;

__device__ __forceinline__ unsigned short f2bf(float f) {
  union { float f; unsigned u; } v; v.f = f;
  unsigned u = v.u;
  u += 0x7fffu + ((u >> 16) & 1u);   // RNE
  return (unsigned short)(u >> 16);
}

// Packed f32x8 -> bf16x8 via v_cvt_pk_bf16_f32
__device__ __forceinline__ short8 cvt8(f32x4 a, f32x4 b) {
  union { __hip_bfloat162 h[4]; short8 s; } u;
  u.h[0] = __float22bfloat162_rn(make_float2(a[0], a[1]));
  u.h[1] = __float22bfloat162_rn(make_float2(a[2], a[3]));
  u.h[2] = __float22bfloat162_rn(make_float2(b[0], b[1]));
  u.h[3] = __float22bfloat162_rn(make_float2(b[2], b[3]));
  return u.s;
}

// ---------------------------------------------------------------------------
// Fused QKV projection (unchanged from R9): gridDim.x = 24 n-blocks.
//   0-7: Q*0.125 -> [b][h][s][dh];  8-15: K -> same;  16-23: V -> [b][h][dh][s]
// ---------------------------------------------------------------------------
__global__ __launch_bounds__(256)
void gemm_qkv(const float* __restrict__ x,
              const float* __restrict__ Qw, const float* __restrict__ Kw,
              const float* __restrict__ Vw,
              unsigned short* __restrict__ Qo, unsigned short* __restrict__ Ko,
              unsigned short* __restrict__ VTo) {
  constexpr int BM = 128, BK = 32, LDK = 40;
  __shared__ __align__(16) short As[BM * LDK];
  __shared__ __align__(16) short Bs[BM * LDK];

  const int nb = blockIdx.x;
  const float* W;
  unsigned short* out;
  float scale = 1.0f;
  int epi;
  if (nb < 8)       { W = Qw; out = Qo;  scale = 0.125f; epi = 1; }
  else if (nb < 16) { W = Kw; out = Ko;  epi = 1; }
  else              { W = Vw; out = VTo; epi = 2; }

  const int tid  = threadIdx.x;
  const int lane = tid & 63;
  const int w    = tid >> 6;
  const int quad = lane >> 4;
  const int l16  = lane & 15;
  const int wm   = (w >> 1) * 64;
  const int wn   = (w & 1) * 64;

  const int m0 = blockIdx.y * BM;
  const int n0 = (nb & 7) * 128;

  f32x4 acc[4][4];
  #pragma unroll
  for (int i = 0; i < 4; ++i)
    #pragma unroll
    for (int j = 0; j < 4; ++j)
      acc[i][j] = (f32x4){0.f, 0.f, 0.f, 0.f};

  for (int k0 = 0; k0 < D_; k0 += BK) {
    __syncthreads();
    #pragma unroll
    for (int i = 0; i < 2; ++i) {
      int flat = i * 256 + tid;
      int row  = flat >> 2;
      int col  = (flat & 3) * 8;
      const float* Ap = x + (size_t)(m0 + row) * D_ + k0 + col;
      *(short8*)(&As[row * LDK + col]) = cvt8(*(const f32x4*)Ap, *(const f32x4*)(Ap + 4));
      const float* Wp = W + (size_t)(n0 + row) * D_ + k0 + col;
      *(short8*)(&Bs[row * LDK + col]) = cvt8(*(const f32x4*)Wp, *(const f32x4*)(Wp + 4));
    }
    __syncthreads();

    short8 af[4], bf[4];
    #pragma unroll
    for (int i = 0; i < 4; ++i)
      af[i] = *(const short8*)(&As[(wm + i * 16 + l16) * LDK + quad * 8]);
    #pragma unroll
    for (int j = 0; j < 4; ++j)
      bf[j] = *(const short8*)(&Bs[(wn + j * 16 + l16) * LDK + quad * 8]);
    #pragma unroll
    for (int i = 0; i < 4; ++i)
      #pragma unroll
      for (int j = 0; j < 4; ++j)
        acc[i][j] = MFMA_BF16_16x16x32(af[i], bf[j], acc[i][j]);
  }

  #pragma unroll
  for (int i = 0; i < 4; ++i)
    #pragma unroll
    for (int j = 0; j < 4; ++j)
      #pragma unroll
      for (int r = 0; r < 4; ++r) {
        int m = m0 + wm + i * 16 + quad * 4 + r;
        int n = n0 + wn + j * 16 + l16;
        unsigned short bv = f2bf(acc[i][j][r] * scale);
        int b = m >> 11, s = m & (S_ - 1);
        int h = n >> 6,  d = n & (DH_ - 1);
        if (epi == 1)
          out[((size_t)(b * H_ + h) * S_ + s) * DH_ + d] = bv;
        else
          out[((size_t)(b * H_ + h) * DH_ + d) * S_ + s] = bv;
      }
}

// ---------------------------------------------------------------------------
// Output projection (unchanged from R9).
// ---------------------------------------------------------------------------
__global__ __launch_bounds__(256)
void gemm_out(const unsigned short* __restrict__ A,
              const float* __restrict__ W,
              float* __restrict__ out) {
  constexpr int BM = 128, BK = 32, LDK = 40;
  __shared__ __align__(16) short As[BM * LDK];
  __shared__ __align__(16) short Bs[BM * LDK];

  const int tid  = threadIdx.x;
  const int lane = tid & 63;
  const int w    = tid >> 6;
  const int quad = lane >> 4;
  const int l16  = lane & 15;
  const int wm   = (w >> 1) * 64;
  const int wn   = (w & 1) * 64;

  const int m0 = blockIdx.y * BM;
  const int n0 = blockIdx.x * 128;

  f32x4 acc[4][4];
  #pragma unroll
  for (int i = 0; i < 4; ++i)
    #pragma unroll
    for (int j = 0; j < 4; ++j)
      acc[i][j] = (f32x4){0.f, 0.f, 0.f, 0.f};

  for (int k0 = 0; k0 < D_; k0 += BK) {
    __syncthreads();
    #pragma unroll
    for (int i = 0; i < 2; ++i) {
      int flat = i * 256 + tid;
      int row  = flat >> 2;
      int col  = (flat & 3) * 8;
      *(short8*)(&As[row * LDK + col]) =
          *(const short8*)(A + (size_t)(m0 + row) * D_ + k0 + col);
      const float* Wp = W + (size_t)(n0 + row) * D_ + k0 + col;
      *(short8*)(&Bs[row * LDK + col]) = cvt8(*(const f32x4*)Wp, *(const f32x4*)(Wp + 4));
    }
    __syncthreads();

    short8 af[4], bf[4];
    #pragma unroll
    for (int i = 0; i < 4; ++i)
      af[i] = *(const short8*)(&As[(wm + i * 16 + l16) * LDK + quad * 8]);
    #pragma unroll
    for (int j = 0; j < 4; ++j)
      bf[j] = *(const short8*)(&Bs[(wn + j * 16 + l16) * LDK + quad * 8]);
    #pragma unroll
    for (int i = 0; i < 4; ++i)
      #pragma unroll
      for (int j = 0; j < 4; ++j)
        acc[i][j] = MFMA_BF16_16x16x32(af[i], bf[j], acc[i][j]);
  }

  #pragma unroll
  for (int i = 0; i < 4; ++i)
    #pragma unroll
    for (int j = 0; j < 4; ++j)
      #pragma unroll
      for (int r = 0; r < 4; ++r) {
        int m = m0 + wm + i * 16 + quad * 4 + r;
        int n = n0 + wn + j * 16 + l16;
        out[(size_t)m * D_ + n] = acc[i][j][r];
      }
}

// ---------------------------------------------------------------------------
// Barrier-free MFMA flash attention. grid = (S/128, H, B), 4 waves/block,
// each wave INDEPENDENTLY owns 32 q-rows and iterates its OWN tile count
// (no __syncthreads anywhere; R9 showed lockstep+barriers = latency-bound,
// 1 wave/SIMD effective).
// K QK-B-frags and VT PV-B-frags are read DIRECTLY from global (the frag
// pattern is 16B/lane contiguous in both layouts); LDS holds only the
// wave-private P round-trip, ordered by s_waitcnt lgkmcnt(0) (intra-wave).
// P stride 68 shorts: scalar P-writes land on disjoint bank groups per quad.
// ---------------------------------------------------------------------------
__global__ __launch_bounds__(256)
void attn(const unsigned short* __restrict__ Q,    // [B][H,S,DH], pre-scaled 1/8
          const unsigned short* __restrict__ K,    // [B][H,S,DH]
          const unsigned short* __restrict__ VT,   // [B][H,DH,S]
          const unsigned char* __restrict__ pmask, // [B][S] (True = masked)
          unsigned short* __restrict__ CTX) {      // [B][S, H*DH]
  constexpr int LDP = 68;
  __shared__ __align__(16) short Ps[4 * 32 * LDP];

  const int tid  = threadIdx.x;
  const int lane = tid & 63;
  const int w    = tid >> 6;
  const int quad = lane >> 4;
  const int l16  = lane & 15;

  const int b  = blockIdx.z;
  const int h  = blockIdx.y;
  const int qt = (gridDim.x - 1) - blockIdx.x;   // heavy blocks first
  const int qw = qt * 128 + w * 32;              // this wave's 32 q-rows

  const unsigned short* Qh = Q  + ((size_t)b * H_ + h) * S_ * DH_;
  const unsigned short* Kh = K  + ((size_t)b * H_ + h) * S_ * DH_;
  const unsigned short* Vh = VT + ((size_t)b * H_ + h) * DH_ * S_;
  const unsigned char* pmb = pmask + (size_t)b * S_;
  unsigned short* CTXb = CTX + (size_t)b * S_ * D_;
  short* Pw = &Ps[w * 32 * LDP];

  // Q fragments (A-layout m=lane&15, k=quad*8+j), loop-invariant
  short8 qf[2][2];
  #pragma unroll
  for (int i = 0; i < 2; ++i)
    #pragma unroll
    for (int c = 0; c < 2; ++c)
      qf[i][c] = *(const short8*)(Qh + (size_t)(qw + i * 16 + l16) * DH_ + c * 32 + quad * 8);

  f32x4 acc[2][4];
  float mrow[2][4], lrow[2][4];
  #pragma unroll
  for (int i = 0; i < 2; ++i)
    #pragma unroll
    for (int t = 0; t < 4; ++t) acc[i][t] = (f32x4){0.f, 0.f, 0.f, 0.f};
  #pragma unroll
  for (int i = 0; i < 2; ++i)
    #pragma unroll
    for (int r = 0; r < 4; ++r) { mrow[i][r] = -1e30f; lrow[i][r] = 0.f; }

  const int ntiles = (qw + 31) / 64 + 1;   // per-wave: keys <= qw+31
  for (int kt = 0; kt < ntiles; ++kt) {
    const int k0 = kt * 64;

    // QK^T: B-frags straight from global K [s][dh]
    f32x4 sc[2][4];
    #pragma unroll
    for (int t = 0; t < 4; ++t) {
      const unsigned short* kp = Kh + (size_t)(k0 + t * 16 + l16) * DH_ + quad * 8;
      short8 kb0 = *(const short8*)kp;
      short8 kb1 = *(const short8*)(kp + 32);
      #pragma unroll
      for (int i = 0; i < 2; ++i) {
        f32x4 z = (f32x4){0.f, 0.f, 0.f, 0.f};
        z = MFMA_BF16_16x16x32(qf[i][0], kb0, z);
        sc[i][t] = MFMA_BF16_16x16x32(qf[i][1], kb1, z);
      }
    }

    // causal + padding mask
    #pragma unroll
    for (int t = 0; t < 4; ++t) {
      int key = k0 + t * 16 + l16;
      bool pad = pmb[key] != 0;
      #pragma unroll
      for (int i = 0; i < 2; ++i)
        #pragma unroll
        for (int r = 0; r < 4; ++r) {
          int qrow = qw + i * 16 + quad * 4 + r;
          if (pad || key > qrow) sc[i][t][r] = -1e30f;
        }
    }

    // online softmax per row (rows spread over the 16 l16 lanes)
    #pragma unroll
    for (int i = 0; i < 2; ++i)
      #pragma unroll
      for (int r = 0; r < 4; ++r) {
        float rm = fmaxf(fmaxf(sc[i][0][r], sc[i][1][r]), fmaxf(sc[i][2][r], sc[i][3][r]));
        #pragma unroll
        for (int off = 8; off; off >>= 1) rm = fmaxf(rm, __shfl_xor(rm, off, 16));
        float mnew = fmaxf(mrow[i][r], rm);
        float al = __expf(mrow[i][r] - mnew);
        float rs = 0.f;
        #pragma unroll
        for (int t = 0; t < 4; ++t) {
          float p = __expf(sc[i][t][r] - mnew);
          sc[i][t][r] = p;
          rs += p;
        }
        #pragma unroll
        for (int off = 8; off; off >>= 1) rs += __shfl_xor(rs, off, 16);
        lrow[i][r] = lrow[i][r] * al + rs;
        mrow[i][r] = mnew;
        #pragma unroll
        for (int t = 0; t < 4; ++t) acc[i][t][r] *= al;
      }

    // P (C-layout) -> wave-private LDS [32 rows][64 keys], stride 68
    #pragma unroll
    for (int i = 0; i < 2; ++i)
      #pragma unroll
      for (int t = 0; t < 4; ++t)
        #pragma unroll
        for (int r = 0; r < 4; ++r)
          Pw[(i * 16 + quad * 4 + r) * LDP + t * 16 + l16] = (short)f2bf(sc[i][t][r]);

    // intra-wave LDS RAW fence: drain ds_writes, block compiler reordering
    asm volatile("s_waitcnt lgkmcnt(0)" ::: "memory");

    // O += P * V: P A-frags from LDS, V B-frags straight from global VT [dh][S]
    #pragma unroll
    for (int ks = 0; ks < 2; ++ks) {
      short8 pa0 = *(const short8*)(&Pw[l16 * LDP + ks * 32 + quad * 8]);
      short8 pa1 = *(const short8*)(&Pw[(16 + l16) * LDP + ks * 32 + quad * 8]);
      #pragma unroll
      for (int t = 0; t < 4; ++t) {
        short8 vb = *(const short8*)(Vh + (size_t)(t * 16 + l16) * S_ + k0 + ks * 32 + quad * 8);
        acc[0][t] = MFMA_BF16_16x16x32(pa0, vb, acc[0][t]);
        acc[1][t] = MFMA_BF16_16x16x32(pa1, vb, acc[1][t]);
      }
    }
  }

  // epilogue: ctx[q, h*64+d] = acc / l
  #pragma unroll
  for (int i = 0; i < 2; ++i)
    #pragma unroll
    for (int r = 0; r < 4; ++r) {
      int qrow = qw + i * 16 + quad * 4 + r;
      float inv = 1.0f / lrow[i][r];
      #pragma unroll
      for (int t = 0; t < 4; ++t)
        CTXb[(size_t)qrow * D_ + h * DH_ + t * 16 + l16] = f2bf(acc[i][t][r] * inv);
    }
}

// ---------------------------------------------------------------------------
// Contract: inputs f32, OUTPUT f32. ws 32 MB (proven R5).
// d_out doubles as staging: Q bf16 [0,16M), CTX bf16 [16M,32M).
// fused-QKV -> attn -> d2d CTX->ws -> final GEMM (reads ws, writes d_out).
// ---------------------------------------------------------------------------
extern "C" void kernel_launch(void* const* d_in, const int* in_sizes, int n_in,
                              void* d_out, int out_size, void* d_ws, size_t ws_size,
                              hipStream_t stream) {
  const float* x  = (const float*)d_in[0];
  const float* Qw = (const float*)d_in[1];
  const float* Kw = (const float*)d_in[2];
  const float* Vw = (const float*)d_in[3];
  const float* Ow = (const float*)d_in[4];
  const unsigned char* pm = (const unsigned char*)d_in[5];

  const size_t NE = (size_t)M_ * D_;
  unsigned short* Qall  = (unsigned short*)d_out;        // 16 MB bf16
  unsigned short* CTXa  = (unsigned short*)d_out + NE;   // 16 MB bf16
  unsigned short* Kall  = (unsigned short*)d_ws;         // 16 MB
  unsigned short* VTall = (unsigned short*)d_ws + NE;    // 16 MB

  gemm_qkv<<<dim3(24, M_ / 128), 256, 0, stream>>>(x, Qw, Kw, Vw,
                                                   Qall, Kall, VTall);

  attn<<<dim3(S_ / 128, H_, B_), 256, 0, stream>>>(Qall, Kall, VTall, pm, CTXa);

  hipMemcpyAsync(d_ws, (const void*)CTXa, NE * sizeof(unsigned short),
                 hipMemcpyDeviceToDevice, stream);

  gemm_out<<<dim3(D_ / 128, M_ / 128), 256, 0, stream>>>((unsigned short*)d_ws,
                                                         Ow, (float*)d_out);
}